// Round 6
// baseline (687.789 us; speedup 1.0000x reference)
//
#include <hip/hip_runtime.h>
#include <hip/hip_fp16.h>
#include <math.h>

#define L_SEQ 1024
#define N_EMB 1024
#define N_HD 512
#define N_ITERS 20
#define EPITCH 1032   // 64 rows x 1032 halfs (pad 8) -> row stride 2064B, 16B aligned
// pls index swizzle (+1 float per 32)
#define PADIDX(c) ((c) + ((c) >> 5))
#define SMEM_FUSED (64 * EPITCH * 2 + 4096 + 4224 + 256 + 256)
// sentinel fill: PUB 20 MB (20it x 16bh x 16chunk x 512 ulong) + VSL 1.25 MB
#define FILL_UINT4 1392640   // 22,282,240 B / 16

typedef short short8 __attribute__((ext_vector_type(8)));   // 8 bf16 = 4 VGPRs
typedef float floatx4 __attribute__((ext_vector_type(4)));  // MFMA acc

__device__ __forceinline__ unsigned short f2bf(float f) {
    unsigned int u = __float_as_uint(f);
    u += 0x7FFFu + ((u >> 16) & 1u);   // round-to-nearest-even
    return (unsigned short)(u >> 16);
}

// ---------------- prep: fp32 -> bf16 ----------------
__global__ __launch_bounds__(256) void convert_x(const float* __restrict__ x,
                                                 unsigned short* __restrict__ xb) {
    const int i = (blockIdx.x * 256 + threadIdx.x) << 4;  // 16 elems/thread
    unsigned short tmp[16];
#pragma unroll
    for (int p = 0; p < 4; ++p) {
        float4 f = *(const float4*)&x[i + (p << 2)];
        tmp[p * 4 + 0] = f2bf(f.x); tmp[p * 4 + 1] = f2bf(f.y);
        tmp[p * 4 + 2] = f2bf(f.z); tmp[p * 4 + 3] = f2bf(f.w);
    }
    *(uint4*)&xb[i]     = *(const uint4*)&tmp[0];
    *(uint4*)&xb[i + 8] = *(const uint4*)&tmp[8];
}

// Transpose all 4 weights to [n][k] bf16. z: 0..2 = Wq/Wk/Wv (1024x512), 3 = Wo (512x1024)
__global__ __launch_bounds__(256) void transpose_all(
    const float* __restrict__ Wq, const float* __restrict__ Wk,
    const float* __restrict__ Wv, const float* __restrict__ Wo,
    unsigned short* __restrict__ wqT, unsigned short* __restrict__ wkT,
    unsigned short* __restrict__ wvT, unsigned short* __restrict__ woT)
{
    const int z = blockIdx.z;
    const float* S; unsigned short* D; int rows, cols;
    if (z == 0)      { S = Wq; D = wqT; rows = 1024; cols = 512; }
    else if (z == 1) { S = Wk; D = wkT; rows = 1024; cols = 512; }
    else if (z == 2) { S = Wv; D = wvT; rows = 1024; cols = 512; }
    else             { S = Wo; D = woT; rows = 512;  cols = 1024; }
    const int n0 = blockIdx.x << 5, k0 = blockIdx.y << 5;
    if (n0 >= cols || k0 >= rows) return;
    __shared__ float Tls[32][33];
    const int t = threadIdx.x;
    const int rl = t >> 5, cl = t & 31;
#pragma unroll
    for (int i = 0; i < 4; ++i)
        Tls[rl + (i << 3)][cl] = S[(size_t)(k0 + rl + (i << 3)) * cols + n0 + cl];
    __syncthreads();
#pragma unroll
    for (int i = 0; i < 4; ++i)
        D[(size_t)(n0 + rl + (i << 3)) * rows + k0 + cl] = f2bf(Tls[cl][rl + (i << 3)]);
}

// ---------------- sentinel prefill (0xFFFFFFFF = negative NaN = "not written") ----
__global__ __launch_bounds__(256) void fill_sentinel(uint4* __restrict__ p) {
    p[blockIdx.x * 256 + threadIdx.x] =
        make_uint4(0xFFFFFFFFu, 0xFFFFFFFFu, 0xFFFFFFFFu, 0xFFFFFFFFu);
}

// ---------------- bf16 MFMA QKV projection ----------------
// q,k bf16 [bh][l][d]; v bf16 TRANSPOSED [bh][d][l]
__global__ __launch_bounds__(256) void mfma_qkv(
    const unsigned short* __restrict__ xb,
    const unsigned short* __restrict__ wqT, const unsigned short* __restrict__ wkT,
    const unsigned short* __restrict__ wvT,
    const float* __restrict__ bq, const float* __restrict__ bk, const float* __restrict__ bv,
    unsigned short* __restrict__ qb, unsigned short* __restrict__ kb,
    unsigned short* __restrict__ vt)
{
    const int pz = blockIdx.z;
    const unsigned short* wT = (pz == 0) ? wqT : (pz == 1) ? wkT : wvT;
    const float* bias = (pz == 0) ? bq : (pz == 1) ? bk : bv;
    __shared__ __align__(16) unsigned short Als[128 * 40];
    __shared__ __align__(16) unsigned short Bls[128 * 40];
    const int t = threadIdx.x;
    const int m0 = blockIdx.y << 7, n0 = blockIdx.x << 7;
    const int w = t >> 6, lane = t & 63;
    const int quad = lane >> 4, l16 = lane & 15;
    const int wr = w >> 1, wc = w & 1;
    const int ra = t >> 2, ka = (t & 3) << 3;
    floatx4 acc[4][4] = {};
    for (int k0 = 0; k0 < N_EMB; k0 += 32) {
        uint4 a0 = *(const uint4*)&xb[(size_t)(m0 + ra) * N_EMB + k0 + ka];
        uint4 a1 = *(const uint4*)&xb[(size_t)(m0 + ra + 64) * N_EMB + k0 + ka];
        uint4 b0 = *(const uint4*)&wT[(size_t)(n0 + ra) * N_EMB + k0 + ka];
        uint4 b1 = *(const uint4*)&wT[(size_t)(n0 + ra + 64) * N_EMB + k0 + ka];
        __syncthreads();
        *(uint4*)&Als[ra * 40 + ka] = a0;
        *(uint4*)&Als[(ra + 64) * 40 + ka] = a1;
        *(uint4*)&Bls[ra * 40 + ka] = b0;
        *(uint4*)&Bls[(ra + 64) * 40 + ka] = b1;
        __syncthreads();
        short8 af[4], bf[4];
#pragma unroll
        for (int i = 0; i < 4; ++i)
            af[i] = *(const short8*)&Als[(wr * 64 + i * 16 + l16) * 40 + quad * 8];
#pragma unroll
        for (int j = 0; j < 4; ++j)
            bf[j] = *(const short8*)&Bls[(wc * 64 + j * 16 + l16) * 40 + quad * 8];
#pragma unroll
        for (int i = 0; i < 4; ++i)
#pragma unroll
            for (int j = 0; j < 4; ++j)
                acc[i][j] = __builtin_amdgcn_mfma_f32_16x16x32_bf16(af[i], bf[j], acc[i][j], 0, 0, 0);
    }
    float bje[4];
    int hh[4], dd[4];
#pragma unroll
    for (int j = 0; j < 4; ++j) {
        int gn = n0 + wc * 64 + j * 16 + l16;
        bje[j] = bias[gn];
        hh[j] = gn >> 6; dd[j] = gn & 63;
    }
    unsigned short* qk = (pz == 0) ? qb : kb;
#pragma unroll
    for (int i = 0; i < 4; ++i)
#pragma unroll
    for (int p = 0; p < 4; ++p) {
        int gm = m0 + wr * 64 + i * 16 + quad * 4 + p;
        int bb = gm >> 10, l = gm & 1023;
#pragma unroll
        for (int j = 0; j < 4; ++j) {
            float val = acc[i][j][p] + bje[j];
            int bh = (bb << 3) + hh[j];
            if (pz < 2) qk[((size_t)bh * L_SEQ + l) * 64 + dd[j]] = f2bf(val);
            else        vt[((size_t)bh << 16) + ((size_t)dd[j] << 10) + l] = f2bf(val);
        }
    }
}

// ---------------- persistent fused: logits + 20 sinkhorn iters + P@V ----------------
// 256 blocks (bh = bid&15, chunk = bid>>4), 1024 threads, 1 block/CU.
// E tile (64 rows x 1024 cols, fp16, pitch 1032) lives entirely in LDS.
// BARRIER-FREE exchange: values are their own ready-flags (all real data is
// positive; sentinel 0xFFFFFFFF has sign bit set). Two-stage segmented reduce:
// publish packed partials -> segment owner reduces 64 cols -> publish v-segment
// -> all gather v. 8.5KB/block/iter cross-block traffic, no counters, no RMW.
__global__ __launch_bounds__(1024, 4) void fused_sinkhorn(
    const unsigned short* __restrict__ qb, const unsigned short* __restrict__ kb,
    const unsigned short* __restrict__ vt, unsigned long long* __restrict__ pub_g,
    unsigned long long* __restrict__ vsl_g, unsigned short* __restrict__ o_p)
{
    extern __shared__ char smem[];
    __half* Eld = (__half*)smem;                                         // 132096 B
    float* vls  = (float*)(smem + 64 * EPITCH * 2);                      // 4096 B
    float* pls  = (float*)(smem + 64 * EPITCH * 2 + 4096);               // 4224 B
    float* uls  = (float*)(smem + 64 * EPITCH * 2 + 4096 + 4224);        // 256 B
    float* vtm  = (float*)(smem + 64 * EPITCH * 2 + 4096 + 4224 + 256);  // 256 B

    const int bid = blockIdx.x;
    const int bh = bid & 15;          // same-bh siblings land on one XCD (perf only)
    const int chunk = bid >> 4;
    const int m0 = chunk << 6;
    const int t = threadIdx.x;
    const int w = t >> 6, lane = t & 63;
    const int quad = lane >> 4, l16 = lane & 15;

    // ---- phase 0: E = exp(Q K^T / 8) -> LDS fp16 ----
    {
        const int wr = w & 3, ns = w >> 2;   // 4 row-subtiles x 4 col-strips of 256
        const size_t qrow = ((size_t)(bh << 10) + m0 + (wr << 4) + l16) * 64;
        short8 af0 = *(const short8*)&qb[qrow + quad * 8];
        short8 af1 = *(const short8*)&qb[qrow + 32 + quad * 8];
        const int erow0 = (wr << 4) + (quad << 2);
        for (int tt = 0; tt < 16; ++tt) {
            const int n0 = (ns << 8) + (tt << 4);
            const size_t krow = ((size_t)(bh << 10) + n0 + l16) * 64;
            short8 bf0 = *(const short8*)&kb[krow + quad * 8];
            short8 bf1 = *(const short8*)&kb[krow + 32 + quad * 8];
            floatx4 acc = {};
            acc = __builtin_amdgcn_mfma_f32_16x16x32_bf16(af0, bf0, acc, 0, 0, 0);
            acc = __builtin_amdgcn_mfma_f32_16x16x32_bf16(af1, bf1, acc, 0, 0, 0);
#pragma unroll
            for (int p = 0; p < 4; ++p)
                Eld[(erow0 + p) * EPITCH + n0 + l16] = __float2half(__expf(acc[p] * 0.125f));
        }
    }
    vls[t] = 1.0f;
    __syncthreads();

    // ---- 20 sinkhorn iterations, E stays in LDS ----
    for (int it = 0; it < N_ITERS; ++it) {
        float vv[16];
#pragma unroll
        for (int p = 0; p < 2; ++p) {
            float4 a = *(const float4*)&vls[(p << 9) + (lane << 3)];
            float4 c = *(const float4*)&vls[(p << 9) + (lane << 3) + 4];
            vv[p * 8 + 0] = a.x; vv[p * 8 + 1] = a.y; vv[p * 8 + 2] = a.z; vv[p * 8 + 3] = a.w;
            vv[p * 8 + 4] = c.x; vv[p * 8 + 5] = c.y; vv[p * 8 + 6] = c.z; vv[p * 8 + 7] = c.w;
        }
        pls[t] = 0.0f;
        if (t < 32) pls[1024 + t] = 0.0f;
        __syncthreads();

        float colacc[16] = {};
#pragma unroll
        for (int rr = 0; rr < 4; ++rr) {
            const int row = (w << 2) + rr;
            float e[16], s = 0.0f;
#pragma unroll
            for (int p = 0; p < 2; ++p) {
                uint4 hx = *(const uint4*)&Eld[row * EPITCH + (p << 9) + (lane << 3)];
                const __half* hp = (const __half*)&hx;
#pragma unroll
                for (int jj = 0; jj < 8; ++jj) {
                    float ev = __half2float(hp[jj]);
                    e[p * 8 + jj] = ev;
                    s += ev * vv[p * 8 + jj];
                }
            }
#pragma unroll
            for (int off = 32; off > 0; off >>= 1) s += __shfl_xor(s, off);
            const float ui = 1.0f / s;
            if (lane == 0) uls[row] = ui;
#pragma unroll
            for (int jj = 0; jj < 16; ++jj) colacc[jj] += e[jj] * ui;
        }
        // LDS combine across the 16 waves (swizzled banks)
#pragma unroll
        for (int p = 0; p < 2; ++p)
#pragma unroll
            for (int jj = 0; jj < 8; ++jj) {
                const int col = (p << 9) + (lane << 3) + jj;
                atomicAdd(&pls[PADIDX(col)], colacc[p * 8 + jj]);
            }
        __syncthreads();

        // publish: 512 packed 8B relaxed stores into this block's private slot
        unsigned long long* pub = pub_g + ((size_t)((it << 4) + bh) << 13) + (chunk << 9);
        if (t < 512) {
            union { float f[2]; unsigned long long u; } pk;
            pk.f[0] = pls[PADIDX(2 * t)];
            pk.f[1] = pls[PADIDX(2 * t + 1)];
            __hip_atomic_store(&pub[t], pk.u, __ATOMIC_RELAXED, __HIP_MEMORY_SCOPE_AGENT);
        }
        __syncthreads();   // protect pls before deposit reuse

        // stage B: this block reduces its own 64-col segment across 16 chunks.
        // data doubles as the ready flag (sign bit set = sentinel, not written).
        if (t < 512) {
            const int c = t >> 5, p = t & 31;
            const unsigned long long* src =
                pub_g + ((size_t)((it << 4) + bh) << 13) + (c << 9) + (chunk << 5) + p;
            unsigned long long x;
            for (;;) {
                x = __hip_atomic_load(src, __ATOMIC_RELAXED, __HIP_MEMORY_SCOPE_AGENT);
                if (!(x & 0x8000000080000000ULL)) break;
                __builtin_amdgcn_s_sleep(2);
            }
            union { unsigned long long u; float f[2]; } un; un.u = x;
            *(float2*)&pls[(c << 6) + (p << 1)] = make_float2(un.f[0], un.f[1]);
        }
        __syncthreads();
        if (t < 64) {
            float s = 0.0f;
#pragma unroll
            for (int c = 0; c < 16; ++c) s += pls[(c << 6) + t];
            vtm[t] = 1.0f / s;
        }
        __syncthreads();
        unsigned long long* vsl = vsl_g + ((size_t)((it << 4) + bh) << 9);
        if (t < 32) {
            union { float f[2]; unsigned long long u; } pk;
            pk.f[0] = vtm[2 * t]; pk.f[1] = vtm[2 * t + 1];
            __hip_atomic_store(&vsl[(chunk << 5) + t], pk.u, __ATOMIC_RELAXED,
                               __HIP_MEMORY_SCOPE_AGENT);
        }
        // stage C: gather the full v vector (poll own ulong until real)
        if (t < 512) {
            unsigned long long x;
            for (;;) {
                x = __hip_atomic_load(&vsl[t], __ATOMIC_RELAXED, __HIP_MEMORY_SCOPE_AGENT);
                if (!(x & 0x8000000080000000ULL)) break;
                __builtin_amdgcn_s_sleep(2);
            }
            union { unsigned long long u; float f[2]; } un; un.u = x;
            vls[2 * t]     = un.f[0];
            vls[2 * t + 1] = un.f[1];
        }
        __syncthreads();
    }

    // ---- P = u * E * v -> bf16 in place (conflict-free, same mapping as sweep) ----
    {
        float vvf[16];
#pragma unroll
        for (int p = 0; p < 2; ++p) {
            float4 a = *(const float4*)&vls[(p << 9) + (lane << 3)];
            float4 c = *(const float4*)&vls[(p << 9) + (lane << 3) + 4];
            vvf[p * 8 + 0] = a.x; vvf[p * 8 + 1] = a.y; vvf[p * 8 + 2] = a.z; vvf[p * 8 + 3] = a.w;
            vvf[p * 8 + 4] = c.x; vvf[p * 8 + 5] = c.y; vvf[p * 8 + 6] = c.z; vvf[p * 8 + 7] = c.w;
        }
#pragma unroll
        for (int rr = 0; rr < 4; ++rr) {
            const int row = (w << 2) + rr;
            const float ur = uls[row];
#pragma unroll
            for (int p = 0; p < 2; ++p) {
                uint4 hx = *(const uint4*)&Eld[row * EPITCH + (p << 9) + (lane << 3)];
                const __half* hp = (const __half*)&hx;
                unsigned short pk[8];
#pragma unroll
                for (int jj = 0; jj < 8; ++jj)
                    pk[jj] = f2bf(__half2float(hp[jj]) * ur * vvf[p * 8 + jj]);
                *(uint4*)&Eld[row * EPITCH + (p << 9) + (lane << 3)] = *(const uint4*)pk;
            }
        }
    }
    __syncthreads();

    // ---- O(64x64) = P(64x1024) @ V : A from LDS (padded pitch), B from vt ----
    {
        const int wr = w >> 2, wc = w & 3;
        const size_t vtb = ((size_t)bh << 16) + ((size_t)((wc << 4) + l16) << 10);
        const int prow = ((wr << 4) + l16) * EPITCH;
        floatx4 oa0 = {}, oa1 = {};
#pragma unroll 4
        for (int ks = 0; ks < 16; ++ks) {
            short8 pa = *(const short8*)&Eld[prow + (ks << 5) + (quad << 3)];
            short8 vb = *(const short8*)&vt[vtb + (ks << 5) + (quad << 3)];
            oa0 = __builtin_amdgcn_mfma_f32_16x16x32_bf16(pa, vb, oa0, 0, 0, 0);
        }
#pragma unroll 4
        for (int ks = 16; ks < 32; ++ks) {
            short8 pa = *(const short8*)&Eld[prow + (ks << 5) + (quad << 3)];
            short8 vb = *(const short8*)&vt[vtb + (ks << 5) + (quad << 3)];
            oa1 = __builtin_amdgcn_mfma_f32_16x16x32_bf16(pa, vb, oa1, 0, 0, 0);
        }
        const int b = bh >> 3, h = bh & 7;
        const int dcol = (wc << 4) + l16;
#pragma unroll
        for (int p = 0; p < 4; ++p) {
            int l = m0 + (wr << 4) + (quad << 2) + p;
            o_p[((size_t)((b << 10) + l) << 9) + (h << 6) + dcol] = f2bf(oa0[p] + oa1[p]);
        }
    }
}

// ---------------- out = out_pre(bf16) @ Wo + bo via MFMA ----------------
__global__ __launch_bounds__(256) void mfma_out(
    const unsigned short* __restrict__ A,   // 2048 x 512 bf16
    const unsigned short* __restrict__ BT,  // woT: 1024 x 512 bf16
    const float* __restrict__ bo, float* __restrict__ C)
{
    __shared__ __align__(16) unsigned short Als[128 * 40];
    __shared__ __align__(16) unsigned short Bls[128 * 40];
    const int t = threadIdx.x;
    const int m0 = blockIdx.y << 7, n0 = blockIdx.x << 7;
    const int w = t >> 6, lane = t & 63;
    const int quad = lane >> 4, l16 = lane & 15;
    const int wr = w >> 1, wc = w & 1;
    const int ra = t >> 2, ka = (t & 3) << 3;
    floatx4 acc[4][4] = {};
    for (int k0 = 0; k0 < N_HD; k0 += 32) {
        uint4 a0 = *(const uint4*)&A[(size_t)(m0 + ra) * N_HD + k0 + ka];
        uint4 a1 = *(const uint4*)&A[(size_t)(m0 + ra + 64) * N_HD + k0 + ka];
        uint4 b0 = *(const uint4*)&BT[(size_t)(n0 + ra) * N_HD + k0 + ka];
        uint4 b1 = *(const uint4*)&BT[(size_t)(n0 + ra + 64) * N_HD + k0 + ka];
        __syncthreads();
        *(uint4*)&Als[ra * 40 + ka] = a0;
        *(uint4*)&Als[(ra + 64) * 40 + ka] = a1;
        *(uint4*)&Bls[ra * 40 + ka] = b0;
        *(uint4*)&Bls[(ra + 64) * 40 + ka] = b1;
        __syncthreads();
        short8 af[4], bf[4];
#pragma unroll
        for (int i = 0; i < 4; ++i)
            af[i] = *(const short8*)&Als[(wr * 64 + i * 16 + l16) * 40 + quad * 8];
#pragma unroll
        for (int j = 0; j < 4; ++j)
            bf[j] = *(const short8*)&Bls[(wc * 64 + j * 16 + l16) * 40 + quad * 8];
#pragma unroll
        for (int i = 0; i < 4; ++i)
#pragma unroll
            for (int j = 0; j < 4; ++j)
                acc[i][j] = __builtin_amdgcn_mfma_f32_16x16x32_bf16(af[i], bf[j], acc[i][j], 0, 0, 0);
    }
    float bje[4];
    int nn[4];
#pragma unroll
    for (int j = 0; j < 4; ++j) {
        nn[j] = n0 + wc * 64 + j * 16 + l16;
        bje[j] = bo[nn[j]];
    }
#pragma unroll
    for (int i = 0; i < 4; ++i)
#pragma unroll
    for (int p = 0; p < 4; ++p) {
        int m = m0 + wr * 64 + i * 16 + quad * 4 + p;
#pragma unroll
        for (int j = 0; j < 4; ++j)
            C[(size_t)m * N_EMB + nn[j]] = acc[i][j][p] + bje[j];
    }
}

extern "C" void kernel_launch(void* const* d_in, const int* in_sizes, int n_in,
                              void* d_out, int out_size, void* d_ws, size_t ws_size,
                              hipStream_t stream)
{
    const float* x  = (const float*)d_in[0];
    const float* Wq = (const float*)d_in[1];
    const float* bq = (const float*)d_in[2];
    const float* Wk = (const float*)d_in[3];
    const float* bk = (const float*)d_in[4];
    const float* Wv = (const float*)d_in[5];
    const float* bv = (const float*)d_in[6];
    const float* Wo = (const float*)d_in[7];
    const float* bo = (const float*)d_in[8];
    float* out = (float*)d_out;

    char* W = (char*)d_ws;
    unsigned short* xb  = (unsigned short*)(W);                    // 4 MB
    unsigned short* wqT = (unsigned short*)(W + (4ll  << 20));     // 1 MB
    unsigned short* wkT = (unsigned short*)(W + (5ll  << 20));     // 1 MB
    unsigned short* wvT = (unsigned short*)(W + (6ll  << 20));     // 1 MB
    unsigned short* woT = (unsigned short*)(W + (7ll  << 20));     // 1 MB
    unsigned short* qb  = (unsigned short*)(W + (8ll  << 20));     // 2 MB
    unsigned short* kb  = (unsigned short*)(W + (10ll << 20));     // 2 MB
    unsigned short* vt  = (unsigned short*)(W + (12ll << 20));     // 2 MB
    unsigned short* o_p = (unsigned short*)(W + (14ll << 20));     // 2 MB
    unsigned long long* pub_g = (unsigned long long*)(W + (16ll << 20));  // 20 MB
    unsigned long long* vsl_g = (unsigned long long*)(W + (36ll << 20));  // 1.25 MB

    convert_x<<<512, 256, 0, stream>>>(x, xb);
    transpose_all<<<dim3(32, 32, 4), 256, 0, stream>>>(Wq, Wk, Wv, Wo, wqT, wkT, wvT, woT);
    fill_sentinel<<<FILL_UINT4 / 256, 256, 0, stream>>>((uint4*)pub_g);  // PUB+VSL contiguous
    mfma_qkv<<<dim3(4, 16, 3), 256, 0, stream>>>(xb, wqT, wkT, wvT, bq, bk, bv, qb, kb, vt);

    void* fargs[] = { (void*)&qb, (void*)&kb, (void*)&vt,
                      (void*)&pub_g, (void*)&vsl_g, (void*)&o_p };
    hipLaunchCooperativeKernel((const void*)fused_sinkhorn, dim3(256), dim3(1024),
                               fargs, SMEM_FUSED, stream);

    mfma_out<<<dim3(8, 16), 256, 0, stream>>>(o_p, woT, bo, out);
}

// Round 7
// 677.594 us; speedup vs baseline: 1.0150x; 1.0150x over previous
//
#include <hip/hip_runtime.h>
#include <hip/hip_fp16.h>
#include <math.h>

#define L_SEQ 1024
#define N_EMB 1024
#define N_HD 512
#define N_ITERS 20
// pls index swizzle (+1 float per 32) for conflict-light LDS atomic combine
#define PADIDX(c) ((c) + ((c) >> 5))

typedef short short8 __attribute__((ext_vector_type(8)));   // 8 bf16 = 4 VGPRs
typedef float floatx4 __attribute__((ext_vector_type(4)));  // MFMA acc

__device__ __forceinline__ unsigned short f2bf(float f) {
    unsigned int u = __float_as_uint(f);
    u += 0x7FFFu + ((u >> 16) & 1u);   // round-to-nearest-even
    return (unsigned short)(u >> 16);
}

// ---------------- prep: fp32 -> bf16 ----------------
__global__ __launch_bounds__(256) void convert_x(const float* __restrict__ x,
                                                 unsigned short* __restrict__ xb) {
    const int i = (blockIdx.x * 256 + threadIdx.x) << 4;  // 16 elems/thread
    unsigned short tmp[16];
#pragma unroll
    for (int p = 0; p < 4; ++p) {
        float4 f = *(const float4*)&x[i + (p << 2)];
        tmp[p * 4 + 0] = f2bf(f.x); tmp[p * 4 + 1] = f2bf(f.y);
        tmp[p * 4 + 2] = f2bf(f.z); tmp[p * 4 + 3] = f2bf(f.w);
    }
    *(uint4*)&xb[i]     = *(const uint4*)&tmp[0];
    *(uint4*)&xb[i + 8] = *(const uint4*)&tmp[8];
}

// Transpose all 4 weights to [n][k] bf16. z: 0..2 = Wq/Wk/Wv (1024x512), 3 = Wo (512x1024)
__global__ __launch_bounds__(256) void transpose_all(
    const float* __restrict__ Wq, const float* __restrict__ Wk,
    const float* __restrict__ Wv, const float* __restrict__ Wo,
    unsigned short* __restrict__ wqT, unsigned short* __restrict__ wkT,
    unsigned short* __restrict__ wvT, unsigned short* __restrict__ woT)
{
    const int z = blockIdx.z;
    const float* S; unsigned short* D; int rows, cols;
    if (z == 0)      { S = Wq; D = wqT; rows = 1024; cols = 512; }
    else if (z == 1) { S = Wk; D = wkT; rows = 1024; cols = 512; }
    else if (z == 2) { S = Wv; D = wvT; rows = 1024; cols = 512; }
    else             { S = Wo; D = woT; rows = 512;  cols = 1024; }
    const int n0 = blockIdx.x << 5, k0 = blockIdx.y << 5;
    if (n0 >= cols || k0 >= rows) return;
    __shared__ float Tls[32][33];
    const int t = threadIdx.x;
    const int rl = t >> 5, cl = t & 31;
#pragma unroll
    for (int i = 0; i < 4; ++i)
        Tls[rl + (i << 3)][cl] = S[(size_t)(k0 + rl + (i << 3)) * cols + n0 + cl];
    __syncthreads();
#pragma unroll
    for (int i = 0; i < 4; ++i)
        D[(size_t)(n0 + rl + (i << 3)) * rows + k0 + cl] = f2bf(Tls[cl][rl + (i << 3)]);
}

// ---------------- bf16 MFMA QKV projection ----------------
// q,k bf16 [bh][l][d]; v bf16 TRANSPOSED [bh][d][l]
__global__ __launch_bounds__(256) void mfma_qkv(
    const unsigned short* __restrict__ xb,
    const unsigned short* __restrict__ wqT, const unsigned short* __restrict__ wkT,
    const unsigned short* __restrict__ wvT,
    const float* __restrict__ bq, const float* __restrict__ bk, const float* __restrict__ bv,
    unsigned short* __restrict__ qb, unsigned short* __restrict__ kb,
    unsigned short* __restrict__ vt)
{
    const int pz = blockIdx.z;
    const unsigned short* wT = (pz == 0) ? wqT : (pz == 1) ? wkT : wvT;
    const float* bias = (pz == 0) ? bq : (pz == 1) ? bk : bv;
    __shared__ __align__(16) unsigned short Als[128 * 40];
    __shared__ __align__(16) unsigned short Bls[128 * 40];
    const int t = threadIdx.x;
    const int m0 = blockIdx.y << 7, n0 = blockIdx.x << 7;
    const int w = t >> 6, lane = t & 63;
    const int quad = lane >> 4, l16 = lane & 15;
    const int wr = w >> 1, wc = w & 1;
    const int ra = t >> 2, ka = (t & 3) << 3;
    floatx4 acc[4][4] = {};
    for (int k0 = 0; k0 < N_EMB; k0 += 32) {
        uint4 a0 = *(const uint4*)&xb[(size_t)(m0 + ra) * N_EMB + k0 + ka];
        uint4 a1 = *(const uint4*)&xb[(size_t)(m0 + ra + 64) * N_EMB + k0 + ka];
        uint4 b0 = *(const uint4*)&wT[(size_t)(n0 + ra) * N_EMB + k0 + ka];
        uint4 b1 = *(const uint4*)&wT[(size_t)(n0 + ra + 64) * N_EMB + k0 + ka];
        __syncthreads();
        *(uint4*)&Als[ra * 40 + ka] = a0;
        *(uint4*)&Als[(ra + 64) * 40 + ka] = a1;
        *(uint4*)&Bls[ra * 40 + ka] = b0;
        *(uint4*)&Bls[(ra + 64) * 40 + ka] = b1;
        __syncthreads();
        short8 af[4], bf[4];
#pragma unroll
        for (int i = 0; i < 4; ++i)
            af[i] = *(const short8*)&Als[(wr * 64 + i * 16 + l16) * 40 + quad * 8];
#pragma unroll
        for (int j = 0; j < 4; ++j)
            bf[j] = *(const short8*)&Bls[(wc * 64 + j * 16 + l16) * 40 + quad * 8];
#pragma unroll
        for (int i = 0; i < 4; ++i)
#pragma unroll
            for (int j = 0; j < 4; ++j)
                acc[i][j] = __builtin_amdgcn_mfma_f32_16x16x32_bf16(af[i], bf[j], acc[i][j], 0, 0, 0);
    }
    float bje[4];
    int hh[4], dd[4];
#pragma unroll
    for (int j = 0; j < 4; ++j) {
        int gn = n0 + wc * 64 + j * 16 + l16;
        bje[j] = bias[gn];
        hh[j] = gn >> 6; dd[j] = gn & 63;
    }
    unsigned short* qk = (pz == 0) ? qb : kb;
#pragma unroll
    for (int i = 0; i < 4; ++i)
#pragma unroll
    for (int p = 0; p < 4; ++p) {
        int gm = m0 + wr * 64 + i * 16 + quad * 4 + p;
        int bb = gm >> 10, l = gm & 1023;
#pragma unroll
        for (int j = 0; j < 4; ++j) {
            float val = acc[i][j][p] + bje[j];
            int bh = (bb << 3) + hh[j];
            if (pz < 2) qk[((size_t)bh * L_SEQ + l) * 64 + dd[j]] = f2bf(val);
            else        vt[((size_t)bh << 16) + ((size_t)dd[j] << 10) + l] = f2bf(val);
        }
    }
}

// ---------------- E = exp(q @ k^T / 8) -> fp16 ----------------
__global__ __launch_bounds__(256) void mfma_logits(
    const unsigned short* __restrict__ qb, const unsigned short* __restrict__ kb,
    __half* __restrict__ E)
{
    const int bh = blockIdx.z;
    const int m0 = blockIdx.y << 7, n0 = blockIdx.x << 7;
    __shared__ __align__(16) unsigned short Qls[128 * 72];
    __shared__ __align__(16) unsigned short Kls[128 * 72];
    const int t = threadIdx.x;
    const int w = t >> 6, lane = t & 63;
    const int quad = lane >> 4, l16 = lane & 15;
    const int wr = w >> 1, wc = w & 1;
    const size_t base = (size_t)bh << 10;
#pragma unroll
    for (int i = 0; i < 4; ++i) {
        int ch = t + (i << 8);
        int row = ch >> 3, ko = (ch & 7) << 3;
        *(uint4*)&Qls[row * 72 + ko] = *(const uint4*)&qb[(base + m0 + row) * 64 + ko];
        *(uint4*)&Kls[row * 72 + ko] = *(const uint4*)&kb[(base + n0 + row) * 64 + ko];
    }
    __syncthreads();
    floatx4 acc[4][4] = {};
#pragma unroll
    for (int kk = 0; kk < 64; kk += 32) {
        short8 af[4], bf[4];
#pragma unroll
        for (int i = 0; i < 4; ++i)
            af[i] = *(const short8*)&Qls[(wr * 64 + i * 16 + l16) * 72 + kk + quad * 8];
#pragma unroll
        for (int j = 0; j < 4; ++j)
            bf[j] = *(const short8*)&Kls[(wc * 64 + j * 16 + l16) * 72 + kk + quad * 8];
#pragma unroll
        for (int i = 0; i < 4; ++i)
#pragma unroll
            for (int j = 0; j < 4; ++j)
                acc[i][j] = __builtin_amdgcn_mfma_f32_16x16x32_bf16(af[i], bf[j], acc[i][j], 0, 0, 0);
    }
#pragma unroll
    for (int i = 0; i < 4; ++i)
#pragma unroll
    for (int p = 0; p < 4; ++p) {
        int gm = m0 + wr * 64 + i * 16 + quad * 4 + p;
#pragma unroll
        for (int j = 0; j < 4; ++j) {
            int gn = n0 + wc * 64 + j * 16 + l16;
            E[((size_t)bh << 20) + ((size_t)gm << 10) + gn] =
                __float2half(__expf(acc[i][j][p] * 0.125f));
        }
    }
}

// ---------------- one full Sinkhorn iteration per launch ----------------
// 256 blocks (bh = bid&15, chunk = bid>>4) x 1024 threads; 64 rows per block.
// Merges the PREVIOUS iteration's 16 chunk-partials locally (absorbs the old
// merge kernel), streams E rows once, computes u + new column partials.
// Kernel boundary = the grid barrier (empirically ~2x cheaper than any
// in-kernel device-scope sync on this chip; rounds 1-6).
__global__ __launch_bounds__(1024, 4) void sink_iter(
    const __half* __restrict__ E, const float* __restrict__ prev,
    float* __restrict__ next, float* __restrict__ u_g, int first)
{
    __shared__ float vls[1024];
    __shared__ float pls[1056];
    const int bid = blockIdx.x;
    const int bh = bid & 15, chunk = bid >> 4;
    const int m0 = chunk << 6;
    const int t = threadIdx.x;
    const int w = t >> 6, lane = t & 63;

    // merge prev partials -> v (or v = 1 on the first iteration)
    if (first) {
        vls[t] = 1.0f;
    } else {
        const float* pb = prev + (bh << 14);
        float s = 0.0f;
#pragma unroll
        for (int c = 0; c < 16; ++c) s += pb[(c << 10) + t];
        vls[t] = 1.0f / s;
    }
    pls[t] = 0.0f;
    if (t < 32) pls[1024 + t] = 0.0f;
    __syncthreads();

    float vv[16];
#pragma unroll
    for (int p = 0; p < 2; ++p) {
        float4 a = *(const float4*)&vls[(p << 9) + (lane << 3)];
        float4 c = *(const float4*)&vls[(p << 9) + (lane << 3) + 4];
        vv[p * 8 + 0] = a.x; vv[p * 8 + 1] = a.y; vv[p * 8 + 2] = a.z; vv[p * 8 + 3] = a.w;
        vv[p * 8 + 4] = c.x; vv[p * 8 + 5] = c.y; vv[p * 8 + 6] = c.z; vv[p * 8 + 7] = c.w;
    }

    float colacc[16] = {};
#pragma unroll
    for (int rr = 0; rr < 4; ++rr) {
        const int row = (w << 2) + rr;
        const __half* Erow = E + ((size_t)((bh << 10) + m0 + row) << 10);
        float e[16], s = 0.0f;
#pragma unroll
        for (int p = 0; p < 2; ++p) {
            uint4 hx = *(const uint4*)&Erow[(p << 9) + (lane << 3)];
            const __half* hp = (const __half*)&hx;
#pragma unroll
            for (int jj = 0; jj < 8; ++jj) {
                float ev = __half2float(hp[jj]);
                e[p * 8 + jj] = ev;
                s += ev * vv[p * 8 + jj];
            }
        }
#pragma unroll
        for (int off = 32; off > 0; off >>= 1) s += __shfl_xor(s, off);
        const float ui = 1.0f / s;
        if (lane == 0) u_g[(bh << 10) + m0 + row] = ui;
#pragma unroll
        for (int jj = 0; jj < 16; ++jj) colacc[jj] += e[jj] * ui;
    }
    // combine the 16 waves' column partials in LDS (swizzled banks)
#pragma unroll
    for (int p = 0; p < 2; ++p)
#pragma unroll
        for (int jj = 0; jj < 8; ++jj) {
            const int col = (p << 9) + (lane << 3) + jj;
            atomicAdd(&pls[PADIDX(col)], colacc[p * 8 + jj]);
        }
    __syncthreads();

    // publish this block's 1024 column partials (plain coalesced stores;
    // the kernel boundary makes them visible to the next launch)
    next[(bh << 14) + (chunk << 10) + t] = pls[PADIDX(t)];
}

// ---------------- out_pre = (u * E * v) @ V via bf16 MFMA ----------------
// also folds the FINAL v-merge (reads the 19th iteration's partial slot)
__global__ __launch_bounds__(256) void attn_mfma(
    const __half* __restrict__ E, const float* __restrict__ u_g,
    const float* __restrict__ vfin, const unsigned short* __restrict__ vt,
    unsigned short* __restrict__ out_pre)
{
    const int bh = blockIdx.y;
    const int m0 = blockIdx.x << 6;
    const int b = bh >> 3, h = bh & 7;
    __shared__ __align__(16) unsigned short Pls[64 * 72];
    __shared__ __align__(16) unsigned short Vls[64 * 72];
    __shared__ float vls[1024];
    __shared__ float uls[64];
    const int t = threadIdx.x;
    const int w = t >> 6, lane = t & 63;
    const int quad = lane >> 4, l16 = lane & 15;

    // final v-merge: sum 16 chunk-partials for each column
#pragma unroll
    for (int jj = 0; jj < 4; ++jj) {
        const int col = t + (jj << 8);
        float s = 0.0f;
#pragma unroll
        for (int c = 0; c < 16; ++c) s += vfin[(bh << 14) + (c << 10) + col];
        vls[col] = 1.0f / s;
    }
    if (t < 64) uls[t] = u_g[(bh << 10) + m0 + t];
    __syncthreads();

    floatx4 acc[4] = {};
    for (int j0 = 0; j0 < L_SEQ; j0 += 64) {
        __syncthreads();
#pragma unroll
        for (int p = 0; p < 2; ++p) {
            int cidx = t + (p << 8);
            int row = cidx >> 3, c8 = (cidx & 7) << 3;
            uint4 hx = *(const uint4*)&E[(((size_t)(bh << 10) + m0 + row) << 10) + j0 + c8];
            const __half* hp = (const __half*)&hx;
            float ur = uls[row];
            float4 v0 = *(const float4*)&vls[j0 + c8];
            float4 v1 = *(const float4*)&vls[j0 + c8 + 4];
            unsigned short pk[8];
            pk[0] = f2bf(__half2float(hp[0]) * ur * v0.x);
            pk[1] = f2bf(__half2float(hp[1]) * ur * v0.y);
            pk[2] = f2bf(__half2float(hp[2]) * ur * v0.z);
            pk[3] = f2bf(__half2float(hp[3]) * ur * v0.w);
            pk[4] = f2bf(__half2float(hp[4]) * ur * v1.x);
            pk[5] = f2bf(__half2float(hp[5]) * ur * v1.y);
            pk[6] = f2bf(__half2float(hp[6]) * ur * v1.z);
            pk[7] = f2bf(__half2float(hp[7]) * ur * v1.w);
            *(uint4*)&Pls[row * 72 + c8] = *(const uint4*)pk;
            *(uint4*)&Vls[row * 72 + c8] =
                *(const uint4*)&vt[((size_t)bh << 16) + ((size_t)row << 10) + j0 + c8];
        }
        __syncthreads();
#pragma unroll
        for (int kk = 0; kk < 64; kk += 32) {
            short8 af = *(const short8*)&Pls[(w * 16 + l16) * 72 + kk + quad * 8];
#pragma unroll
            for (int j = 0; j < 4; ++j) {
                short8 bfv = *(const short8*)&Vls[(j * 16 + l16) * 72 + kk + quad * 8];
                acc[j] = __builtin_amdgcn_mfma_f32_16x16x32_bf16(af, bfv, acc[j], 0, 0, 0);
            }
        }
    }
#pragma unroll
    for (int j = 0; j < 4; ++j)
#pragma unroll
    for (int p = 0; p < 4; ++p) {
        int l = m0 + w * 16 + quad * 4 + p;
        int d = (j << 4) + l16;
        out_pre[((size_t)((b << 10) + l)) * N_HD + (h << 6) + d] = f2bf(acc[j][p]);
    }
}

// ---------------- out = out_pre(bf16) @ Wo + bo via MFMA ----------------
__global__ __launch_bounds__(256) void mfma_out(
    const unsigned short* __restrict__ A,   // 2048 x 512 bf16
    const unsigned short* __restrict__ BT,  // woT: 1024 x 512 bf16
    const float* __restrict__ bo, float* __restrict__ C)
{
    __shared__ __align__(16) unsigned short Als[128 * 40];
    __shared__ __align__(16) unsigned short Bls[128 * 40];
    const int t = threadIdx.x;
    const int m0 = blockIdx.y << 7, n0 = blockIdx.x << 7;
    const int w = t >> 6, lane = t & 63;
    const int quad = lane >> 4, l16 = lane & 15;
    const int wr = w >> 1, wc = w & 1;
    const int ra = t >> 2, ka = (t & 3) << 3;
    floatx4 acc[4][4] = {};
    for (int k0 = 0; k0 < N_HD; k0 += 32) {
        uint4 a0 = *(const uint4*)&A[(size_t)(m0 + ra) * N_HD + k0 + ka];
        uint4 a1 = *(const uint4*)&A[(size_t)(m0 + ra + 64) * N_HD + k0 + ka];
        uint4 b0 = *(const uint4*)&BT[(size_t)(n0 + ra) * N_HD + k0 + ka];
        uint4 b1 = *(const uint4*)&BT[(size_t)(n0 + ra + 64) * N_HD + k0 + ka];
        __syncthreads();
        *(uint4*)&Als[ra * 40 + ka] = a0;
        *(uint4*)&Als[(ra + 64) * 40 + ka] = a1;
        *(uint4*)&Bls[ra * 40 + ka] = b0;
        *(uint4*)&Bls[(ra + 64) * 40 + ka] = b1;
        __syncthreads();
        short8 af[4], bf[4];
#pragma unroll
        for (int i = 0; i < 4; ++i)
            af[i] = *(const short8*)&Als[(wr * 64 + i * 16 + l16) * 40 + quad * 8];
#pragma unroll
        for (int j = 0; j < 4; ++j)
            bf[j] = *(const short8*)&Bls[(wc * 64 + j * 16 + l16) * 40 + quad * 8];
#pragma unroll
        for (int i = 0; i < 4; ++i)
#pragma unroll
            for (int j = 0; j < 4; ++j)
                acc[i][j] = __builtin_amdgcn_mfma_f32_16x16x32_bf16(af[i], bf[j], acc[i][j], 0, 0, 0);
    }
    float bje[4];
    int nn[4];
#pragma unroll
    for (int j = 0; j < 4; ++j) {
        nn[j] = n0 + wc * 64 + j * 16 + l16;
        bje[j] = bo[nn[j]];
    }
#pragma unroll
    for (int i = 0; i < 4; ++i)
#pragma unroll
    for (int p = 0; p < 4; ++p) {
        int m = m0 + wr * 64 + i * 16 + quad * 4 + p;
#pragma unroll
        for (int j = 0; j < 4; ++j)
            C[(size_t)m * N_EMB + nn[j]] = acc[i][j][p] + bje[j];
    }
}

extern "C" void kernel_launch(void* const* d_in, const int* in_sizes, int n_in,
                              void* d_out, int out_size, void* d_ws, size_t ws_size,
                              hipStream_t stream)
{
    const float* x  = (const float*)d_in[0];
    const float* Wq = (const float*)d_in[1];
    const float* bq = (const float*)d_in[2];
    const float* Wk = (const float*)d_in[3];
    const float* bk = (const float*)d_in[4];
    const float* Wv = (const float*)d_in[5];
    const float* bv = (const float*)d_in[6];
    const float* Wo = (const float*)d_in[7];
    const float* bo = (const float*)d_in[8];
    float* out = (float*)d_out;

    char* W = (char*)d_ws;
    unsigned short* xb  = (unsigned short*)(W);                    // 4 MB
    unsigned short* wqT = (unsigned short*)(W + (4ll  << 20));     // 1 MB
    unsigned short* wkT = (unsigned short*)(W + (5ll  << 20));     // 1 MB
    unsigned short* wvT = (unsigned short*)(W + (6ll  << 20));     // 1 MB
    unsigned short* woT = (unsigned short*)(W + (7ll  << 20));     // 1 MB
    unsigned short* qb  = (unsigned short*)(W + (8ll  << 20));     // 2 MB
    unsigned short* kb  = (unsigned short*)(W + (10ll << 20));     // 2 MB
    unsigned short* vt  = (unsigned short*)(W + (12ll << 20));     // 2 MB
    unsigned short* o_p = (unsigned short*)(W + (14ll << 20));     // 2 MB
    __half* E           = (__half*)(W + (16ll << 20));             // 32 MB
    float* part0        = (float*)(W + (48ll << 20));              // 1 MB
    float* part1        = (float*)(W + (49ll << 20));              // 1 MB
    float* u_g          = (float*)(W + (50ll << 20));              // 64 KB

    convert_x<<<512, 256, 0, stream>>>(x, xb);
    transpose_all<<<dim3(32, 32, 4), 256, 0, stream>>>(Wq, Wk, Wv, Wo, wqT, wkT, wvT, woT);
    mfma_qkv<<<dim3(4, 16, 3), 256, 0, stream>>>(xb, wqT, wkT, wvT, bq, bk, bv, qb, kb, vt);
    mfma_logits<<<dim3(8, 8, 16), 256, 0, stream>>>(qb, kb, E);

    for (int it = 0; it < N_ITERS; ++it) {
        const float* prev = (it & 1) ? part0 : part1;
        float* next       = (it & 1) ? part1 : part0;
        sink_iter<<<256, 1024, 0, stream>>>(E, prev, next, u_g, it == 0);
    }
    // N_ITERS=20 -> last write was slot (19&1)=1
    attn_mfma<<<dim3(16, 16), 256, 0, stream>>>(E, u_g, part1, vt, o_p);
    mfma_out<<<dim3(8, 16), 256, 0, stream>>>(o_p, woT, bo, out);
}